// Round 1
// baseline (228.420 us; speedup 1.0000x reference)
//
#include <hip/hip_runtime.h>
#include <math.h>

// TimeEmbedding: out[b][i] = sin(t[b]*f_i) if i even else cos(t[b]*f_i),
// f_i = 10000^(-i/256), B=524288, D=512, f32 out (1 GiB). Write-BW-bound.

#define D_MODEL 512

__device__ __forceinline__ float sin_rev(float r) {
    // r in revolutions; v_fract + v_sin (HW sin takes revolutions)
    return __builtin_amdgcn_sinf(__builtin_amdgcn_fractf(r));
}
__device__ __forceinline__ float cos_rev(float r) {
    return __builtin_amdgcn_cosf(__builtin_amdgcn_fractf(r));
}

__global__ __launch_bounds__(256) void time_embed_kernel(
    const float* __restrict__ t, float4* __restrict__ out, int n_rows) {
    // 128 float4-lanes per row (D=512). Grid-stride keeps (idx & 127) fixed
    // per thread -> the 4 frequencies are loop-invariant.
    const int d0 = (threadIdx.x & 127) * 4;

    const float LOG2_10000_OVER_256 = 0.051904345232615426f; // log2(10000)/256
    const float INV_2PI = 0.15915494309189535f;

    // inv_freq_i / (2*pi): frequency in revolutions per unit t
    const float f0 = __builtin_amdgcn_exp2f(-(float)(d0 + 0) * LOG2_10000_OVER_256) * INV_2PI;
    const float f1 = __builtin_amdgcn_exp2f(-(float)(d0 + 1) * LOG2_10000_OVER_256) * INV_2PI;
    const float f2 = __builtin_amdgcn_exp2f(-(float)(d0 + 2) * LOG2_10000_OVER_256) * INV_2PI;
    const float f3 = __builtin_amdgcn_exp2f(-(float)(d0 + 3) * LOG2_10000_OVER_256) * INV_2PI;

    const size_t total = (size_t)n_rows * (D_MODEL / 4);
    const size_t stride = (size_t)gridDim.x * blockDim.x;
    for (size_t idx = (size_t)blockIdx.x * blockDim.x + threadIdx.x; idx < total;
         idx += stride) {
        const float tv = t[idx >> 7];  // 128 lanes share one row's t -> cache broadcast
        float4 o;
        o.x = sin_rev(tv * f0);  // d0+0 even -> sin
        o.y = cos_rev(tv * f1);  // d0+1 odd  -> cos
        o.z = sin_rev(tv * f2);
        o.w = cos_rev(tv * f3);
        out[idx] = o;
    }
}

extern "C" void kernel_launch(void* const* d_in, const int* in_sizes, int n_in,
                              void* d_out, int out_size, void* d_ws, size_t ws_size,
                              hipStream_t stream) {
    const float* t = (const float*)d_in[0];
    float4* out = (float4*)d_out;
    const int n_rows = in_sizes[0];  // 524288
    // 2048 blocks x 256 threads = 524288 threads (multiple of 128 -> d0 invariant)
    time_embed_kernel<<<dim3(2048), dim3(256), 0, stream>>>(t, out, n_rows);
}

// Round 2
// 220.071 us; speedup vs baseline: 1.0379x; 1.0379x over previous
//
#include <hip/hip_runtime.h>
#include <math.h>

// TimeEmbedding: out[b][i] = sin(t[b]*f_i) if i even else cos(t[b]*f_i),
// f_i = 10000^(-i/256), B=524288, D=512, f32 out (1 GiB). Write-BW-bound.
//
// R1 structure: one wave = one row per iteration.
//  - lane c (0..63) writes float4 #c and #(c+64) of the row -> two fully
//    contiguous 1KB wave-stores, nontemporal (bypass L2 alloc; stream never re-read)
//  - t[row] is wave-uniform (one broadcast dword), prefetched 1 iter ahead
//  - 8 frequencies per lane are loop-invariant (8 exp2 total per thread)

#define D_MODEL 512

typedef float f32x4 __attribute__((ext_vector_type(4)));

__device__ __forceinline__ float sin_rev(float r) {
    return __builtin_amdgcn_sinf(__builtin_amdgcn_fractf(r));  // HW sin takes revolutions
}
__device__ __forceinline__ float cos_rev(float r) {
    return __builtin_amdgcn_cosf(__builtin_amdgcn_fractf(r));
}

__global__ __launch_bounds__(256) void time_embed_kernel(
    const float* __restrict__ t, f32x4* __restrict__ out, int n_rows) {
    const int g = blockIdx.x * 256 + threadIdx.x;
    const int c = g & 63;                 // float4 slot within row (first half)
    const size_t w = (size_t)(g >> 6);    // wave id = starting row
    const size_t nw = (size_t)(gridDim.x * 256) >> 6;  // total waves = 8192

    const float LOG2_10000_OVER_256 = 0.051904345232615426f; // log2(10000)/256
    const float INV_2PI = 0.15915494309189535f;

    const int d0a = 4 * c;        // columns d0a..d0a+3
    const int d0b = 4 * c + 256;  // columns d0b..d0b+3 (second half of row)

    float fa[4], fb[4];
#pragma unroll
    for (int j = 0; j < 4; ++j) {
        fa[j] = __builtin_amdgcn_exp2f(-(float)(d0a + j) * LOG2_10000_OVER_256) * INV_2PI;
        fb[j] = __builtin_amdgcn_exp2f(-(float)(d0b + j) * LOG2_10000_OVER_256) * INV_2PI;
    }

    if (w >= (size_t)n_rows) return;
    float tv = t[w];  // wave-uniform broadcast load
    for (size_t r = w; r < (size_t)n_rows; r += nw) {
        // prefetch next row's t (hide load latency under this row's compute+stores)
        const size_t rn = r + nw;
        const float tn = t[rn < (size_t)n_rows ? rn : r];

        f32x4 oa, ob;
        oa.x = sin_rev(tv * fa[0]);  // even col -> sin
        oa.y = cos_rev(tv * fa[1]);  // odd col  -> cos
        oa.z = sin_rev(tv * fa[2]);
        oa.w = cos_rev(tv * fa[3]);
        ob.x = sin_rev(tv * fb[0]);
        ob.y = cos_rev(tv * fb[1]);
        ob.z = sin_rev(tv * fb[2]);
        ob.w = cos_rev(tv * fb[3]);

        f32x4* rowp = out + r * (D_MODEL / 4);
        __builtin_nontemporal_store(oa, rowp + c);       // contiguous 1KB / wave
        __builtin_nontemporal_store(ob, rowp + 64 + c);  // contiguous 1KB / wave

        tv = tn;
    }
}

extern "C" void kernel_launch(void* const* d_in, const int* in_sizes, int n_in,
                              void* d_out, int out_size, void* d_ws, size_t ws_size,
                              hipStream_t stream) {
    const float* t = (const float*)d_in[0];
    f32x4* out = (f32x4*)d_out;
    const int n_rows = in_sizes[0];  // 524288
    // 2048 blocks x 256 threads = 8192 waves; 64 rows per wave
    time_embed_kernel<<<dim3(2048), dim3(256), 0, stream>>>(t, out, n_rows);
}

// Round 3
// 201.684 us; speedup vs baseline: 1.1326x; 1.0912x over previous
//
#include <hip/hip_runtime.h>
#include <math.h>

// TimeEmbedding: out[b][i] = sin(t[b]*f_i) if i even else cos(t[b]*f_i),
// f_i = 10000^(-i/256), B=524288, D=512, f32 out (1 GiB). Write-BW-bound.
//
// R3 structure: wave w owns 64 CONSECUTIVE rows [w*64, w*64+64), processed
// 4 rows/iteration:
//  - 8 KB contiguous stores per iteration (8x dwordx4 wave-stores in flight
//    before register reuse), PLAIN stores (no nt -> L2 write-back combining,
//    like the 6.6 TB/s fill kernel)
//  - t for a row-quad = one wave-uniform float4 broadcast load, prefetched
//    one quad ahead (branchless clamped address)
//  - 8 frequencies per lane are loop-invariant (8 exp2 total per thread)

#define D_MODEL 512

typedef float f32x4 __attribute__((ext_vector_type(4)));

__device__ __forceinline__ float sin_rev(float r) {
    return __builtin_amdgcn_sinf(__builtin_amdgcn_fractf(r));  // HW sin takes revolutions
}
__device__ __forceinline__ float cos_rev(float r) {
    return __builtin_amdgcn_cosf(__builtin_amdgcn_fractf(r));
}

__global__ __launch_bounds__(256) void time_embed_kernel(
    const float* __restrict__ t, f32x4* __restrict__ out, int n_rows) {
    const int g = blockIdx.x * 256 + threadIdx.x;
    const int c = g & 63;        // float4 slot within row (and +64 for 2nd half)
    const int w = g >> 6;        // wave id; wave owns rows [w*64, w*64+64)

    const float LOG2_10000_OVER_256 = 0.051904345232615426f; // log2(10000)/256
    const float INV_2PI = 0.15915494309189535f;

    float fa[4], fb[4];
#pragma unroll
    for (int j = 0; j < 4; ++j) {
        fa[j] = __builtin_amdgcn_exp2f(-(float)(4 * c + j) * LOG2_10000_OVER_256) * INV_2PI;
        fb[j] = __builtin_amdgcn_exp2f(-(float)(4 * c + 256 + j) * LOG2_10000_OVER_256) * INV_2PI;
    }

    const int row0 = w * 64;
    if (row0 >= n_rows) return;
    const float* tw = t + row0;                 // 64 t-values for this wave
    f32x4* outw = out + (size_t)row0 * (D_MODEL / 4);

    f32x4 tq = *(const f32x4*)tw;               // wave-uniform broadcast (quad 0)
#pragma unroll 4
    for (int q = 0; q < 16; ++q) {
        // branchless clamped prefetch of the next quad's t
        const int qn = (q < 15) ? (q + 1) : q;
        const f32x4 tnext = *(const f32x4*)(tw + 4 * qn);

#pragma unroll
        for (int j = 0; j < 4; ++j) {           // j is compile-time (rule #20)
            const float tv = tq[j];
            f32x4 oa, ob;
            oa.x = sin_rev(tv * fa[0]);         // even col -> sin
            oa.y = cos_rev(tv * fa[1]);         // odd col  -> cos
            oa.z = sin_rev(tv * fa[2]);
            oa.w = cos_rev(tv * fa[3]);
            ob.x = sin_rev(tv * fb[0]);
            ob.y = cos_rev(tv * fb[1]);
            ob.z = sin_rev(tv * fb[2]);
            ob.w = cos_rev(tv * fb[3]);
            f32x4* rowp = outw + (size_t)(4 * q + j) * (D_MODEL / 4);
            rowp[c] = oa;                       // contiguous 1KB wave-store
            rowp[64 + c] = ob;                  // contiguous 1KB wave-store
        }
        tq = tnext;
    }
}

extern "C" void kernel_launch(void* const* d_in, const int* in_sizes, int n_in,
                              void* d_out, int out_size, void* d_ws, size_t ws_size,
                              hipStream_t stream) {
    const float* t = (const float*)d_in[0];
    f32x4* out = (f32x4*)d_out;
    const int n_rows = in_sizes[0];  // 524288 = 8192 waves * 64 rows
    time_embed_kernel<<<dim3(2048), dim3(256), 0, stream>>>(t, out, n_rows);
}